// Round 1
// baseline (691.543 us; speedup 1.0000x reference)
//
#include <hip/hip_runtime.h>
#include <math.h>

#define NF 256     // features / hidden width
#define NHEADS 8
#define BM 128
#define BN 128
#define BK 16

// ---------------- CSR build ----------------

__global__ __launch_bounds__(256) void deg_init_k(int* __restrict__ deg, int n) {
    int i = blockIdx.x * 256 + threadIdx.x;
    if (i < n) deg[i] = 1;  // self loop
}

__global__ __launch_bounds__(256) void deg_count_k(const int* __restrict__ dst, int* __restrict__ deg, int E) {
    int e = blockIdx.x * 256 + threadIdx.x;
    if (e < E) atomicAdd(&deg[dst[e]], 1);
}

__global__ __launch_bounds__(1024) void scan_k(const int* __restrict__ deg, int* __restrict__ indptr, int n) {
    __shared__ int part[1024];
    int tid = threadIdx.x;
    int chunk = (n + 1023) >> 10;
    int s = tid * chunk;
    int e = s + chunk; if (e > n) e = n; if (s > n) s = n;
    int sum = 0;
    for (int i = s; i < e; ++i) sum += deg[i];
    part[tid] = sum;
    __syncthreads();
    for (int off = 1; off < 1024; off <<= 1) {
        int v = 0;
        if (tid >= off) v = part[tid - off];
        __syncthreads();
        if (tid >= off) part[tid] += v;
        __syncthreads();
    }
    int run = (tid > 0) ? part[tid - 1] : 0;
    for (int i = s; i < e; ++i) { indptr[i] = run; run += deg[i]; }
    if (tid == 1023) indptr[n] = part[1023];
}

__global__ __launch_bounds__(256) void fill_self_k(const int* __restrict__ indptr, int* __restrict__ cursor,
                                                   int* __restrict__ srcs, int n) {
    int i = blockIdx.x * 256 + threadIdx.x;
    if (i < n) { int p = indptr[i]; srcs[p] = i; cursor[i] = p + 1; }
}

__global__ __launch_bounds__(256) void fill_edge_k(const int* __restrict__ esrc, const int* __restrict__ edst,
                                                   int* __restrict__ cursor, int* __restrict__ srcs, int E) {
    int e = blockIdx.x * 256 + threadIdx.x;
    if (e < E) {
        int p = atomicAdd(&cursor[edst[e]], 1);
        srcs[p] = esrc[e];
    }
}

// ---------------- f32 GEMM: C[M,N] = A[M,K] @ B[K,N] ----------------

__global__ __launch_bounds__(256) void gemm_k(const float* __restrict__ A, const float* __restrict__ B,
                                              float* __restrict__ C, int M, int N, int K) {
    __shared__ float As[BK][BM + 4];
    __shared__ float Bs[BK][BN + 4];
    int t = threadIdx.x;
    int bm = blockIdx.x * BM;
    int bn = blockIdx.y * BN;
    int tx = t & 15, ty = t >> 4;
    float acc[8][8];
#pragma unroll
    for (int i = 0; i < 8; ++i)
#pragma unroll
        for (int j = 0; j < 8; ++j) acc[i][j] = 0.f;

    for (int k0 = 0; k0 < K; k0 += BK) {
#pragma unroll
        for (int L = 0; L < 2; ++L) {
            int f = t + L * 256;
            int ar = f >> 2, ak = (f & 3) * 4;
            int grow = bm + ar;
            float4 av = make_float4(0.f, 0.f, 0.f, 0.f);
            if (grow < M) av = *(const float4*)&A[(size_t)grow * K + k0 + ak];
            As[ak + 0][ar] = av.x; As[ak + 1][ar] = av.y; As[ak + 2][ar] = av.z; As[ak + 3][ar] = av.w;
            int bk = f >> 5, bc = (f & 31) * 4;
            float4 bv = *(const float4*)&B[(size_t)(k0 + bk) * N + bn + bc];
            *(float4*)&Bs[bk][bc] = bv;
        }
        __syncthreads();
#pragma unroll
        for (int kk = 0; kk < BK; ++kk) {
            float4 a0 = *(const float4*)&As[kk][ty * 8];
            float4 a1 = *(const float4*)&As[kk][ty * 8 + 4];
            float4 b0 = *(const float4*)&Bs[kk][tx * 4];
            float4 b1 = *(const float4*)&Bs[kk][64 + tx * 4];
            float ar8[8] = {a0.x, a0.y, a0.z, a0.w, a1.x, a1.y, a1.z, a1.w};
            float br8[8] = {b0.x, b0.y, b0.z, b0.w, b1.x, b1.y, b1.z, b1.w};
#pragma unroll
            for (int i = 0; i < 8; ++i)
#pragma unroll
                for (int j = 0; j < 8; ++j) acc[i][j] += ar8[i] * br8[j];
        }
        __syncthreads();
    }
#pragma unroll
    for (int i = 0; i < 8; ++i) {
        int row = bm + ty * 8 + i;
        if (row >= M) continue;
        float4 v0 = {acc[i][0], acc[i][1], acc[i][2], acc[i][3]};
        float4 v1 = {acc[i][4], acc[i][5], acc[i][6], acc[i][7]};
        *(float4*)&C[(size_t)row * N + bn + tx * 4] = v0;
        *(float4*)&C[(size_t)row * N + bn + 64 + tx * 4] = v1;
    }
}

// ---------------- per-node attention scalars ----------------
// lane l covers global channels [4l,4l+4) of row; head = l>>3.

__global__ __launch_bounds__(256) void alpha_k(const float* __restrict__ h, const float* __restrict__ att_s,
                                               const float* __restrict__ att_d, float* __restrict__ aS,
                                               float* __restrict__ aD, int N) {
    int wid = blockIdx.x * 4 + (threadIdx.x >> 6);
    if (wid >= N) return;
    int lane = threadIdx.x & 63;
    float4 hv = ((const float4*)h)[(size_t)wid * 64 + lane];
    float4 sv = ((const float4*)att_s)[lane];
    float4 dv = ((const float4*)att_d)[lane];
    float ps = hv.x * sv.x + hv.y * sv.y + hv.z * sv.z + hv.w * sv.w;
    float pd = hv.x * dv.x + hv.y * dv.y + hv.z * dv.z + hv.w * dv.w;
    ps += __shfl_xor(ps, 1); ps += __shfl_xor(ps, 2); ps += __shfl_xor(ps, 4);
    pd += __shfl_xor(pd, 1); pd += __shfl_xor(pd, 2); pd += __shfl_xor(pd, 4);
    if ((lane & 7) == 0) {
        int head = lane >> 3;
        aS[(size_t)wid * NHEADS + head] = ps;
        aD[(size_t)wid * NHEADS + head] = pd;
    }
}

// ---------------- aggregation (layers 1 & 2): wave per dst, online softmax ----------------

template <bool ELU>
__global__ __launch_bounds__(256) void agg_k(const float* __restrict__ h, const float* __restrict__ aS,
                                             const float* __restrict__ aD, const int* __restrict__ indptr,
                                             const int* __restrict__ srcs, const float* __restrict__ bias,
                                             float* __restrict__ out, int N) {
    int wid = blockIdx.x * 4 + (threadIdx.x >> 6);
    if (wid >= N) return;
    int lane = threadIdx.x & 63;
    int hh = lane >> 3;
    float ad = aD[(size_t)wid * NHEADS + hh];
    int beg = indptr[wid], end = indptr[wid + 1];
    const float4* h4 = (const float4*)h;
    float m = -INFINITY, den = 0.f;
    float ax = 0.f, ay = 0.f, az = 0.f, aw = 0.f;
    for (int k = beg; k < end; ++k) {
        int s = srcs[k];
        float e = aS[(size_t)s * NHEADS + hh] + ad;
        e = (e > 0.f) ? e : 0.2f * e;               // leaky_relu(0.2)
        float mn = fmaxf(m, e);
        float sc = expf(m - mn);                    // first iter: exp(-inf)=0
        float p  = expf(e - mn);
        float4 hv = h4[(size_t)s * 64 + lane];
        den = den * sc + p;
        ax = ax * sc + p * hv.x;
        ay = ay * sc + p * hv.y;
        az = az * sc + p * hv.z;
        aw = aw * sc + p * hv.w;
        m = mn;
    }
    float inv = 1.f / (den + 1e-16f);
    float4 bv = ((const float4*)bias)[lane];
    float o0 = ax * inv + bv.x, o1 = ay * inv + bv.y, o2 = az * inv + bv.z, o3 = aw * inv + bv.w;
    if (ELU) {
        o0 = (o0 > 0.f) ? o0 : expm1f(o0);
        o1 = (o1 > 0.f) ? o1 : expm1f(o1);
        o2 = (o2 > 0.f) ? o2 : expm1f(o2);
        o3 = (o3 > 0.f) ? o3 : expm1f(o3);
    }
    float4 ov = {o0, o1, o2, o3};
    ((float4*)out)[(size_t)wid * 64 + lane] = ov;
}

// ---------------- layer 3: [256]->[2] matvec + att scalars (wave per node) ----------------

__global__ __launch_bounds__(256) void l3_k(const float* __restrict__ x, const float* __restrict__ W3,
                                            const float* __restrict__ att_s, const float* __restrict__ att_d,
                                            float* __restrict__ h3, float* __restrict__ s3,
                                            float* __restrict__ d3, int N) {
    int wid = blockIdx.x * 4 + (threadIdx.x >> 6);
    if (wid >= N) return;
    int lane = threadIdx.x & 63;
    float4 xv = ((const float4*)x)[(size_t)wid * 64 + lane];
    // W3 row-major [256,2]: float4 pair covers channels 4l..4l+3 for both outputs
    float4 wa = ((const float4*)W3)[lane * 2];
    float4 wb = ((const float4*)W3)[lane * 2 + 1];
    float p0 = xv.x * wa.x + xv.y * wa.z + xv.z * wb.x + xv.w * wb.z;
    float p1 = xv.x * wa.y + xv.y * wa.w + xv.z * wb.y + xv.w * wb.w;
#pragma unroll
    for (int off = 1; off < 64; off <<= 1) {
        p0 += __shfl_xor(p0, off);
        p1 += __shfl_xor(p1, off);
    }
    if (lane == 0) {
        h3[(size_t)wid * 2] = p0;
        h3[(size_t)wid * 2 + 1] = p1;
        s3[wid] = p0 * att_s[0] + p1 * att_s[1];
        d3[wid] = p0 * att_d[0] + p1 * att_d[1];
    }
}

// ---------------- layer 3 aggregation: thread per dst node ----------------

__global__ __launch_bounds__(256) void agg3_k(const float* __restrict__ h3, const float* __restrict__ s3,
                                              const float* __restrict__ d3, const int* __restrict__ indptr,
                                              const int* __restrict__ srcs, const float* __restrict__ b3,
                                              float* __restrict__ out, int N) {
    int n = blockIdx.x * 256 + threadIdx.x;
    if (n >= N) return;
    float ad = d3[n];
    float m = -INFINITY, den = 0.f, a0 = 0.f, a1 = 0.f;
    int beg = indptr[n], end = indptr[n + 1];
    for (int k = beg; k < end; ++k) {
        int s = srcs[k];
        float e = s3[s] + ad;
        e = (e > 0.f) ? e : 0.2f * e;
        float mn = fmaxf(m, e);
        float sc = expf(m - mn);
        float p  = expf(e - mn);
        den = den * sc + p;
        a0 = a0 * sc + p * h3[(size_t)s * 2];
        a1 = a1 * sc + p * h3[(size_t)s * 2 + 1];
        m = mn;
    }
    float inv = 1.f / (den + 1e-16f);
    out[(size_t)n * 2]     = a0 * inv + b3[0];
    out[(size_t)n * 2 + 1] = a1 * inv + b3[1];
}

// ---------------- launch ----------------

extern "C" void kernel_launch(void* const* d_in, const int* in_sizes, int n_in,
                              void* d_out, int out_size, void* d_ws, size_t ws_size,
                              hipStream_t stream) {
    const float* x   = (const float*)d_in[0];
    const int*   ei  = (const int*)d_in[1];
    const float* W1  = (const float*)d_in[2];
    const float* as1 = (const float*)d_in[3];
    const float* ad1 = (const float*)d_in[4];
    const float* b1  = (const float*)d_in[5];
    const float* W2  = (const float*)d_in[6];
    const float* as2 = (const float*)d_in[7];
    const float* ad2 = (const float*)d_in[8];
    const float* b2  = (const float*)d_in[9];
    const float* W3  = (const float*)d_in[10];
    const float* at_s3 = (const float*)d_in[11];
    const float* at_d3 = (const float*)d_in[12];
    const float* b3  = (const float*)d_in[13];

    int N = in_sizes[0] / NF;   // 50000
    int E = in_sizes[1] / 2;    // 800000
    const int* esrc = ei;
    const int* edst = ei + E;

    char* w = (char*)d_ws;
    float* hbuf  = (float*)w; w += (size_t)N * NF * 4;
    float* xnext = (float*)w; w += (size_t)N * NF * 4;
    float* aS    = (float*)w; w += (size_t)N * NHEADS * 4;
    float* aD    = (float*)w; w += (size_t)N * NHEADS * 4;
    float* h3    = (float*)w; w += (size_t)N * 2 * 4;
    float* s3    = (float*)w; w += (size_t)N * 4;
    float* d3    = (float*)w; w += (size_t)N * 4;
    int* deg     = (int*)w; w += (size_t)N * 4;
    int* indptr  = (int*)w; w += (size_t)(N + 1) * 4 + 60;
    int* cursor  = (int*)w; w += (size_t)N * 4;
    int* srcs    = (int*)w;

    int nb_n = (N + 255) / 256;
    int nb_e = (E + 255) / 256;
    int nb_w = (N + 3) / 4;

    // CSR build (dst-grouped, incl. self loops)
    deg_init_k<<<nb_n, 256, 0, stream>>>(deg, N);
    deg_count_k<<<nb_e, 256, 0, stream>>>(edst, deg, E);
    scan_k<<<1, 1024, 0, stream>>>(deg, indptr, N);
    fill_self_k<<<nb_n, 256, 0, stream>>>(indptr, cursor, srcs, N);
    fill_edge_k<<<nb_e, 256, 0, stream>>>(esrc, edst, cursor, srcs, E);

    dim3 gg((N + BM - 1) / BM, NF / BN);

    // layer 1
    gemm_k<<<gg, 256, 0, stream>>>(x, W1, hbuf, N, NF, NF);
    alpha_k<<<nb_w, 256, 0, stream>>>(hbuf, as1, ad1, aS, aD, N);
    agg_k<true><<<nb_w, 256, 0, stream>>>(hbuf, aS, aD, indptr, srcs, b1, xnext, N);
    // layer 2
    gemm_k<<<gg, 256, 0, stream>>>(xnext, W2, hbuf, N, NF, NF);
    alpha_k<<<nb_w, 256, 0, stream>>>(hbuf, as2, ad2, aS, aD, N);
    agg_k<true><<<nb_w, 256, 0, stream>>>(hbuf, aS, aD, indptr, srcs, b2, xnext, N);
    // layer 3
    l3_k<<<nb_w, 256, 0, stream>>>(xnext, W3, at_s3, at_d3, h3, s3, d3, N);
    agg3_k<<<nb_n, 256, 0, stream>>>(h3, s3, d3, indptr, srcs, b3, (float*)d_out, N);
}

// Round 2
// 490.935 us; speedup vs baseline: 1.4086x; 1.4086x over previous
//
#include <hip/hip_runtime.h>
#include <math.h>

#define NF 256
#define NHEADS 8

typedef _Float16 half8 __attribute__((ext_vector_type(8)));
typedef _Float16 half4 __attribute__((ext_vector_type(4)));
typedef float f32x4 __attribute__((ext_vector_type(4)));

// ---------------- CSR build ----------------

__global__ __launch_bounds__(256) void deg_init_k(int* __restrict__ deg, int n) {
    int i = blockIdx.x * 256 + threadIdx.x;
    if (i < n) deg[i] = 1;  // self loop
}

__global__ __launch_bounds__(256) void deg_count_k(const int* __restrict__ dst, int* __restrict__ deg, int E) {
    int e = blockIdx.x * 256 + threadIdx.x;
    if (e < E) atomicAdd(&deg[dst[e]], 1);
}

__global__ __launch_bounds__(1024) void scan_k(const int* __restrict__ deg, int* __restrict__ indptr, int n) {
    __shared__ int part[1024];
    int tid = threadIdx.x;
    int chunk = (n + 1023) >> 10;
    int s = tid * chunk;
    int e = s + chunk; if (e > n) e = n; if (s > n) s = n;
    int sum = 0;
    for (int i = s; i < e; ++i) sum += deg[i];
    part[tid] = sum;
    __syncthreads();
    for (int off = 1; off < 1024; off <<= 1) {
        int v = 0;
        if (tid >= off) v = part[tid - off];
        __syncthreads();
        if (tid >= off) part[tid] += v;
        __syncthreads();
    }
    int run = (tid > 0) ? part[tid - 1] : 0;
    for (int i = s; i < e; ++i) { indptr[i] = run; run += deg[i]; }
    if (tid == 1023) indptr[n] = part[1023];
}

__global__ __launch_bounds__(256) void fill_self_k(const int* __restrict__ indptr, int* __restrict__ cursor,
                                                   int* __restrict__ srcs, int n) {
    int i = blockIdx.x * 256 + threadIdx.x;
    if (i < n) { int p = indptr[i]; srcs[p] = i; cursor[i] = p + 1; }
}

__global__ __launch_bounds__(256) void fill_edge_k(const int* __restrict__ esrc, const int* __restrict__ edst,
                                                   int* __restrict__ cursor, int* __restrict__ srcs, int E) {
    int e = blockIdx.x * 256 + threadIdx.x;
    if (e < E) {
        int p = atomicAdd(&cursor[edst[e]], 1);
        srcs[p] = esrc[e];
    }
}

// ---------------- MFMA f16 GEMM: C[M,256] = A[M,256] @ W[256,256], C fp16 ----------------
// Block: 512 thr = 8 waves (2m x 4n). Block tile 256 rows x 256 cols. Whole W^T in LDS fp16.
// A-frags loaded directly from global (16B/lane, line-covered); AF32: convert f32->f16 in regs.

template <int AF32>
__global__ __launch_bounds__(512, 2) void gemm_mfma_k(const void* __restrict__ Av, const float* __restrict__ W,
                                                      _Float16* __restrict__ C, int M) {
    __shared__ __align__(16) _Float16 WT[256][264];  // [col][k], 528B row stride
    int t = threadIdx.x;
    {
        int cq = (t & 7) | ((t >> 6) << 3);  // col-quad 0..63 (cols 4cq..4cq+3)
        int ko = (t >> 3) & 7;               // k-oct
        for (int it = 0; it < 4; ++it) {
            int kb = it * 64 + ko * 8;
            float wv[8][4];
#pragma unroll
            for (int j = 0; j < 8; ++j) {
                float4 v = *(const float4*)&W[(size_t)(kb + j) * 256 + cq * 4];
                wv[j][0] = v.x; wv[j][1] = v.y; wv[j][2] = v.z; wv[j][3] = v.w;
            }
#pragma unroll
            for (int c = 0; c < 4; ++c) {
                half8 p;
#pragma unroll
                for (int j = 0; j < 8; ++j) p[j] = (_Float16)wv[j][c];
                *(half8*)&WT[cq * 4 + c][kb] = p;
            }
        }
    }
    __syncthreads();

    int wave = t >> 6, lane = t & 63;
    int wm = wave >> 2, wn = wave & 3;   // 2 x 4 wave grid
    int lr = lane & 15, lg = lane >> 4;
    int r0 = blockIdx.x * 256 + wm * 128;
    int c0 = wn * 64;
    const float* Af = (const float*)Av;
    const _Float16* Ah = (const _Float16*)Av;

    f32x4 acc[8][4];
#pragma unroll
    for (int mr = 0; mr < 8; ++mr)
#pragma unroll
        for (int nr = 0; nr < 4; ++nr) acc[mr][nr] = (f32x4){0.f, 0.f, 0.f, 0.f};

    for (int ks = 0; ks < 8; ++ks) {
        int k0 = ks * 32;
        half8 a[8];
#pragma unroll
        for (int mr = 0; mr < 8; ++mr) {
            int row = r0 + mr * 16 + lr;
            row = row < M ? row : M - 1;
            if (AF32) {
                const float* p = Af + (size_t)row * 256 + k0 + lg * 8;
                float4 x0 = *(const float4*)p;
                float4 x1 = *(const float4*)(p + 4);
                half8 av;
                av[0] = (_Float16)x0.x; av[1] = (_Float16)x0.y; av[2] = (_Float16)x0.z; av[3] = (_Float16)x0.w;
                av[4] = (_Float16)x1.x; av[5] = (_Float16)x1.y; av[6] = (_Float16)x1.z; av[7] = (_Float16)x1.w;
                a[mr] = av;
            } else {
                a[mr] = *(const half8*)(Ah + (size_t)row * 256 + k0 + lg * 8);
            }
        }
        half8 b[4];
#pragma unroll
        for (int nr = 0; nr < 4; ++nr)
            b[nr] = *(const half8*)&WT[c0 + nr * 16 + lr][k0 + lg * 8];
#pragma unroll
        for (int mr = 0; mr < 8; ++mr)
#pragma unroll
            for (int nr = 0; nr < 4; ++nr)
                acc[mr][nr] = __builtin_amdgcn_mfma_f32_16x16x32_f16(a[mr], b[nr], acc[mr][nr], 0, 0, 0);
    }

#pragma unroll
    for (int mr = 0; mr < 8; ++mr) {
        int rbase = r0 + mr * 16 + lg * 4;
#pragma unroll
        for (int j = 0; j < 4; ++j) {
            int row = rbase + j;
            if (row < M) {
#pragma unroll
                for (int nr = 0; nr < 4; ++nr)
                    C[(size_t)row * 256 + c0 + nr * 16 + lr] = (_Float16)acc[mr][nr][j];
            }
        }
    }
}

// ---------------- per-node attention scalars (h fp16) ----------------

__global__ __launch_bounds__(256) void alpha_k(const _Float16* __restrict__ h, const float* __restrict__ att_s,
                                               const float* __restrict__ att_d, float* __restrict__ aS,
                                               float* __restrict__ aD, int N) {
    int wid = blockIdx.x * 4 + (threadIdx.x >> 6);
    if (wid >= N) return;
    int lane = threadIdx.x & 63;
    half4 hv = ((const half4*)h)[(size_t)wid * 64 + lane];
    float4 sv = ((const float4*)att_s)[lane];
    float4 dv = ((const float4*)att_d)[lane];
    float h0 = (float)hv[0], h1 = (float)hv[1], h2 = (float)hv[2], h3 = (float)hv[3];
    float ps = h0 * sv.x + h1 * sv.y + h2 * sv.z + h3 * sv.w;
    float pd = h0 * dv.x + h1 * dv.y + h2 * dv.z + h3 * dv.w;
    ps += __shfl_xor(ps, 1); ps += __shfl_xor(ps, 2); ps += __shfl_xor(ps, 4);
    pd += __shfl_xor(pd, 1); pd += __shfl_xor(pd, 2); pd += __shfl_xor(pd, 4);
    if ((lane & 7) == 0) {
        int head = lane >> 3;
        aS[(size_t)wid * NHEADS + head] = ps;
        aD[(size_t)wid * NHEADS + head] = pd;
    }
}

// ---------------- aggregation: wave per dst, deferred-max online softmax, fp16 gather ----------------

template <bool ELU>
__global__ __launch_bounds__(256) void agg_k(const _Float16* __restrict__ h, const float* __restrict__ aS,
                                             const float* __restrict__ aD, const int* __restrict__ indptr,
                                             const int* __restrict__ srcs, const float* __restrict__ bias,
                                             _Float16* __restrict__ out, int N) {
    int wid = blockIdx.x * 4 + (threadIdx.x >> 6);
    if (wid >= N) return;
    int lane = threadIdx.x & 63;
    int hh = lane >> 3;
    float ad = aD[(size_t)wid * NHEADS + hh];
    int beg = indptr[wid], end = indptr[wid + 1];
    const half4* h4p = (const half4*)h;
    float m = -INFINITY, den = 0.f;
    float ax = 0.f, ay = 0.f, az = 0.f, aw = 0.f;
    int s = srcs[beg];
    float asv = aS[(size_t)s * NHEADS + hh];
    for (int k = beg; k < end; ++k) {
        int snext = (k + 1 < end) ? srcs[k + 1] : 0;
        float asn = aS[(size_t)snext * NHEADS + hh];   // prefetch next
        float e = asv + ad;
        e = (e > 0.f) ? e : 0.2f * e;                  // leaky_relu(0.2)
        if (__any(e > m + 8.f)) {                      // rare, wave-uniform rescale
            float mn = fmaxf(m, e);
            float sc = __expf(m - mn);                 // first iter: exp(-inf)=0
            den *= sc; ax *= sc; ay *= sc; az *= sc; aw *= sc;
            m = mn;
        }
        float p = __expf(e - m);                       // bounded by e^8
        half4 hv = h4p[(size_t)s * 64 + lane];
        den += p;
        ax += p * (float)hv[0];
        ay += p * (float)hv[1];
        az += p * (float)hv[2];
        aw += p * (float)hv[3];
        s = snext; asv = asn;
    }
    float inv = 1.f / (den + 1e-16f);
    float4 bv = ((const float4*)bias)[lane];
    float o0 = ax * inv + bv.x, o1 = ay * inv + bv.y, o2 = az * inv + bv.z, o3 = aw * inv + bv.w;
    if (ELU) {
        o0 = (o0 > 0.f) ? o0 : expm1f(o0);
        o1 = (o1 > 0.f) ? o1 : expm1f(o1);
        o2 = (o2 > 0.f) ? o2 : expm1f(o2);
        o3 = (o3 > 0.f) ? o3 : expm1f(o3);
    }
    half4 ov;
    ov[0] = (_Float16)o0; ov[1] = (_Float16)o1; ov[2] = (_Float16)o2; ov[3] = (_Float16)o3;
    ((half4*)out)[(size_t)wid * 64 + lane] = ov;
}

// ---------------- layer 3: [256]->[2] matvec + att scalars (wave per node, x fp16) ----------------

__global__ __launch_bounds__(256) void l3_k(const _Float16* __restrict__ x, const float* __restrict__ W3,
                                            const float* __restrict__ att_s, const float* __restrict__ att_d,
                                            float* __restrict__ h3, float* __restrict__ s3,
                                            float* __restrict__ d3, int N) {
    int wid = blockIdx.x * 4 + (threadIdx.x >> 6);
    if (wid >= N) return;
    int lane = threadIdx.x & 63;
    half4 xv = ((const half4*)x)[(size_t)wid * 64 + lane];
    float x0 = (float)xv[0], x1 = (float)xv[1], x2 = (float)xv[2], x3 = (float)xv[3];
    float4 wa = ((const float4*)W3)[lane * 2];
    float4 wb = ((const float4*)W3)[lane * 2 + 1];
    float p0 = x0 * wa.x + x1 * wa.z + x2 * wb.x + x3 * wb.z;
    float p1 = x0 * wa.y + x1 * wa.w + x2 * wb.y + x3 * wb.w;
#pragma unroll
    for (int off = 1; off < 64; off <<= 1) {
        p0 += __shfl_xor(p0, off);
        p1 += __shfl_xor(p1, off);
    }
    if (lane == 0) {
        h3[(size_t)wid * 2] = p0;
        h3[(size_t)wid * 2 + 1] = p1;
        s3[wid] = p0 * att_s[0] + p1 * att_s[1];
        d3[wid] = p0 * att_d[0] + p1 * att_d[1];
    }
}

// ---------------- layer 3 aggregation: thread per dst node ----------------

__global__ __launch_bounds__(256) void agg3_k(const float* __restrict__ h3, const float* __restrict__ s3,
                                              const float* __restrict__ d3, const int* __restrict__ indptr,
                                              const int* __restrict__ srcs, const float* __restrict__ b3,
                                              float* __restrict__ out, int N) {
    int n = blockIdx.x * 256 + threadIdx.x;
    if (n >= N) return;
    float ad = d3[n];
    float m = -INFINITY, den = 0.f, a0 = 0.f, a1 = 0.f;
    int beg = indptr[n], end = indptr[n + 1];
    for (int k = beg; k < end; ++k) {
        int s = srcs[k];
        float e = s3[s] + ad;
        e = (e > 0.f) ? e : 0.2f * e;
        if (e > m + 8.f) {
            float mn = fmaxf(m, e);
            float sc = __expf(m - mn);
            den *= sc; a0 *= sc; a1 *= sc;
            m = mn;
        }
        float p = __expf(e - m);
        den += p;
        a0 += p * h3[(size_t)s * 2];
        a1 += p * h3[(size_t)s * 2 + 1];
    }
    float inv = 1.f / (den + 1e-16f);
    out[(size_t)n * 2]     = a0 * inv + b3[0];
    out[(size_t)n * 2 + 1] = a1 * inv + b3[1];
}

// ---------------- launch ----------------

extern "C" void kernel_launch(void* const* d_in, const int* in_sizes, int n_in,
                              void* d_out, int out_size, void* d_ws, size_t ws_size,
                              hipStream_t stream) {
    const float* x   = (const float*)d_in[0];
    const int*   ei  = (const int*)d_in[1];
    const float* W1  = (const float*)d_in[2];
    const float* as1 = (const float*)d_in[3];
    const float* ad1 = (const float*)d_in[4];
    const float* b1  = (const float*)d_in[5];
    const float* W2  = (const float*)d_in[6];
    const float* as2 = (const float*)d_in[7];
    const float* ad2 = (const float*)d_in[8];
    const float* b2  = (const float*)d_in[9];
    const float* W3  = (const float*)d_in[10];
    const float* at_s3 = (const float*)d_in[11];
    const float* at_d3 = (const float*)d_in[12];
    const float* b3  = (const float*)d_in[13];

    int N = in_sizes[0] / NF;   // 50000
    int E = in_sizes[1] / 2;    // 800000
    const int* esrc = ei;
    const int* edst = ei + E;

    char* w = (char*)d_ws;
    _Float16* hbuf  = (_Float16*)w; w += (size_t)N * NF * 2;
    _Float16* xnext = (_Float16*)w; w += (size_t)N * NF * 2;
    float* aS    = (float*)w; w += (size_t)N * NHEADS * 4;
    float* aD    = (float*)w; w += (size_t)N * NHEADS * 4;
    float* h3    = (float*)w; w += (size_t)N * 2 * 4;
    float* s3    = (float*)w; w += (size_t)N * 4;
    float* d3    = (float*)w; w += (size_t)N * 4;
    int* deg     = (int*)w; w += (size_t)N * 4;
    int* indptr  = (int*)w; w += (size_t)(N + 1) * 4 + 60;
    int* cursor  = (int*)w; w += (size_t)N * 4;
    int* srcs    = (int*)w;

    int nb_n = (N + 255) / 256;
    int nb_e = (E + 255) / 256;
    int nb_w = (N + 3) / 4;
    int nb_g = (N + 255) / 256;  // 196 blocks of 256 rows

    // CSR build (dst-grouped, incl. self loops)
    deg_init_k<<<nb_n, 256, 0, stream>>>(deg, N);
    deg_count_k<<<nb_e, 256, 0, stream>>>(edst, deg, E);
    scan_k<<<1, 1024, 0, stream>>>(deg, indptr, N);
    fill_self_k<<<nb_n, 256, 0, stream>>>(indptr, cursor, srcs, N);
    fill_edge_k<<<nb_e, 256, 0, stream>>>(esrc, edst, cursor, srcs, E);

    // layer 1
    gemm_mfma_k<1><<<nb_g, 512, 0, stream>>>(x, W1, hbuf, N);
    alpha_k<<<nb_w, 256, 0, stream>>>(hbuf, as1, ad1, aS, aD, N);
    agg_k<true><<<nb_w, 256, 0, stream>>>(hbuf, aS, aD, indptr, srcs, b1, xnext, N);
    // layer 2
    gemm_mfma_k<0><<<nb_g, 512, 0, stream>>>(xnext, W2, hbuf, N);
    alpha_k<<<nb_w, 256, 0, stream>>>(hbuf, as2, ad2, aS, aD, N);
    agg_k<true><<<nb_w, 256, 0, stream>>>(hbuf, aS, aD, indptr, srcs, b2, xnext, N);
    // layer 3
    l3_k<<<nb_w, 256, 0, stream>>>(xnext, W3, at_s3, at_d3, h3, s3, d3, N);
    agg3_k<<<nb_n, 256, 0, stream>>>(h3, s3, d3, indptr, srcs, b3, (float*)d_out, N);
}

// Round 3
// 404.295 us; speedup vs baseline: 1.7105x; 1.2143x over previous
//
#include <hip/hip_runtime.h>
#include <math.h>

#define NF 256
#define NHEADS 8
#define MNEG -1e30f

typedef _Float16 half8 __attribute__((ext_vector_type(8)));
typedef _Float16 half4 __attribute__((ext_vector_type(4)));
typedef float f32x4 __attribute__((ext_vector_type(4)));

// ---------------- CSR build ----------------

__global__ __launch_bounds__(256) void deg_init_k(int* __restrict__ deg, int n) {
    int i = blockIdx.x * 256 + threadIdx.x;
    if (i < n) deg[i] = 1;  // self loop
}

__global__ __launch_bounds__(256) void deg_count_k(const int* __restrict__ dst, int* __restrict__ deg, int E) {
    int e = blockIdx.x * 256 + threadIdx.x;
    if (e < E) atomicAdd(&deg[dst[e]], 1);
}

__global__ __launch_bounds__(1024) void scan_k(const int* __restrict__ deg, int* __restrict__ indptr, int n) {
    __shared__ int part[1024];
    int tid = threadIdx.x;
    int chunk = (n + 1023) >> 10;
    int s = tid * chunk;
    int e = s + chunk; if (e > n) e = n; if (s > n) s = n;
    int sum = 0;
    for (int i = s; i < e; ++i) sum += deg[i];
    part[tid] = sum;
    __syncthreads();
    for (int off = 1; off < 1024; off <<= 1) {
        int v = 0;
        if (tid >= off) v = part[tid - off];
        __syncthreads();
        if (tid >= off) part[tid] += v;
        __syncthreads();
    }
    int run = (tid > 0) ? part[tid - 1] : 0;
    for (int i = s; i < e; ++i) { indptr[i] = run; run += deg[i]; }
    if (tid == 1023) indptr[n] = part[1023];
}

__global__ __launch_bounds__(256) void fill_self_k(const int* __restrict__ indptr, int* __restrict__ cursor,
                                                   int* __restrict__ srcs, int n) {
    int i = blockIdx.x * 256 + threadIdx.x;
    if (i < n) { int p = indptr[i]; srcs[p] = i; cursor[i] = p + 1; }
}

__global__ __launch_bounds__(256) void fill_edge_k(const int* __restrict__ esrc, const int* __restrict__ edst,
                                                   int* __restrict__ cursor, int* __restrict__ srcs, int E) {
    int e = blockIdx.x * 256 + threadIdx.x;
    if (e < E) {
        int p = atomicAdd(&cursor[edst[e]], 1);
        srcs[p] = esrc[e];
    }
}

// ---------------- MFMA f16 GEMM: C[M,256] = A[M,256] @ W[256,256], C fp16 ----------------

template <int AF32>
__global__ __launch_bounds__(512, 2) void gemm_mfma_k(const void* __restrict__ Av, const float* __restrict__ W,
                                                      _Float16* __restrict__ C, int M) {
    __shared__ __align__(16) _Float16 WT[256][264];  // [col][k], 528B row stride
    int t = threadIdx.x;
    {
        int cq = (t & 7) | ((t >> 6) << 3);  // col-quad 0..63 (cols 4cq..4cq+3)
        int ko = (t >> 3) & 7;               // k-oct
        for (int it = 0; it < 4; ++it) {
            int kb = it * 64 + ko * 8;
            float wv[8][4];
#pragma unroll
            for (int j = 0; j < 8; ++j) {
                float4 v = *(const float4*)&W[(size_t)(kb + j) * 256 + cq * 4];
                wv[j][0] = v.x; wv[j][1] = v.y; wv[j][2] = v.z; wv[j][3] = v.w;
            }
#pragma unroll
            for (int c = 0; c < 4; ++c) {
                half8 p;
#pragma unroll
                for (int j = 0; j < 8; ++j) p[j] = (_Float16)wv[j][c];
                *(half8*)&WT[cq * 4 + c][kb] = p;
            }
        }
    }
    __syncthreads();

    int wave = t >> 6, lane = t & 63;
    int wm = wave >> 2, wn = wave & 3;   // 2 x 4 wave grid
    int lr = lane & 15, lg = lane >> 4;
    int r0 = blockIdx.x * 256 + wm * 128;
    int c0 = wn * 64;
    const float* Af = (const float*)Av;
    const _Float16* Ah = (const _Float16*)Av;

    f32x4 acc[8][4];
#pragma unroll
    for (int mr = 0; mr < 8; ++mr)
#pragma unroll
        for (int nr = 0; nr < 4; ++nr) acc[mr][nr] = (f32x4){0.f, 0.f, 0.f, 0.f};

    for (int ks = 0; ks < 8; ++ks) {
        int k0 = ks * 32;
        half8 a[8];
#pragma unroll
        for (int mr = 0; mr < 8; ++mr) {
            int row = r0 + mr * 16 + lr;
            row = row < M ? row : M - 1;
            if (AF32) {
                const float* p = Af + (size_t)row * 256 + k0 + lg * 8;
                float4 x0 = *(const float4*)p;
                float4 x1 = *(const float4*)(p + 4);
                half8 av;
                av[0] = (_Float16)x0.x; av[1] = (_Float16)x0.y; av[2] = (_Float16)x0.z; av[3] = (_Float16)x0.w;
                av[4] = (_Float16)x1.x; av[5] = (_Float16)x1.y; av[6] = (_Float16)x1.z; av[7] = (_Float16)x1.w;
                a[mr] = av;
            } else {
                a[mr] = *(const half8*)(Ah + (size_t)row * 256 + k0 + lg * 8);
            }
        }
        half8 b[4];
#pragma unroll
        for (int nr = 0; nr < 4; ++nr)
            b[nr] = *(const half8*)&WT[c0 + nr * 16 + lr][k0 + lg * 8];
#pragma unroll
        for (int mr = 0; mr < 8; ++mr)
#pragma unroll
            for (int nr = 0; nr < 4; ++nr)
                acc[mr][nr] = __builtin_amdgcn_mfma_f32_16x16x32_f16(a[mr], b[nr], acc[mr][nr], 0, 0, 0);
    }

#pragma unroll
    for (int mr = 0; mr < 8; ++mr) {
        int rbase = r0 + mr * 16 + lg * 4;
#pragma unroll
        for (int j = 0; j < 4; ++j) {
            int row = rbase + j;
            if (row < M) {
#pragma unroll
                for (int nr = 0; nr < 4; ++nr)
                    C[(size_t)row * 256 + c0 + nr * 16 + lr] = (_Float16)acc[mr][nr][j];
            }
        }
    }
}

// ---------------- per-node attention scalars (h fp16) ----------------

__global__ __launch_bounds__(256) void alpha_k(const _Float16* __restrict__ h, const float* __restrict__ att_s,
                                               const float* __restrict__ att_d, float* __restrict__ aS,
                                               float* __restrict__ aD, int N) {
    int wid = blockIdx.x * 4 + (threadIdx.x >> 6);
    if (wid >= N) return;
    int lane = threadIdx.x & 63;
    half4 hv = ((const half4*)h)[(size_t)wid * 64 + lane];
    float4 sv = ((const float4*)att_s)[lane];
    float4 dv = ((const float4*)att_d)[lane];
    float h0 = (float)hv[0], h1 = (float)hv[1], h2 = (float)hv[2], h3 = (float)hv[3];
    float ps = h0 * sv.x + h1 * sv.y + h2 * sv.z + h3 * sv.w;
    float pd = h0 * dv.x + h1 * dv.y + h2 * dv.z + h3 * dv.w;
    ps += __shfl_xor(ps, 1); ps += __shfl_xor(ps, 2); ps += __shfl_xor(ps, 4);
    pd += __shfl_xor(pd, 1); pd += __shfl_xor(pd, 2); pd += __shfl_xor(pd, 4);
    if ((lane & 7) == 0) {
        int head = lane >> 3;
        aS[(size_t)wid * NHEADS + head] = ps;
        aD[(size_t)wid * NHEADS + head] = pd;
    }
}

// ---------------- aggregation: wave per dst, 4-edge unroll, deferred-max online softmax ----------------

template <bool ELU>
__global__ __launch_bounds__(256) void agg_k(const _Float16* __restrict__ h, const float* __restrict__ aS,
                                             const float* __restrict__ aD, const int* __restrict__ indptr,
                                             const int* __restrict__ srcs, const float* __restrict__ bias,
                                             _Float16* __restrict__ out, int N) {
    int wid = blockIdx.x * 4 + (threadIdx.x >> 6);
    if (wid >= N) return;
    int lane = threadIdx.x & 63;
    int hh = lane >> 3;
    float ad = aD[(size_t)wid * NHEADS + hh];
    int beg = indptr[wid], end = indptr[wid + 1];
    const half4* h4p = (const half4*)h;
    float m = MNEG, den = 0.f;
    float ax = 0.f, ay = 0.f, az = 0.f, aw = 0.f;
    int k = beg;
    for (; k + 4 <= end; k += 4) {
        int s0 = srcs[k], s1 = srcs[k + 1], s2 = srcs[k + 2], s3 = srcs[k + 3];
        float as0 = aS[(size_t)s0 * NHEADS + hh];
        float as1 = aS[(size_t)s1 * NHEADS + hh];
        float as2 = aS[(size_t)s2 * NHEADS + hh];
        float as3 = aS[(size_t)s3 * NHEADS + hh];
        half4 v0 = h4p[(size_t)s0 * 64 + lane];   // 4 gathers in flight
        half4 v1 = h4p[(size_t)s1 * 64 + lane];
        half4 v2 = h4p[(size_t)s2 * 64 + lane];
        half4 v3 = h4p[(size_t)s3 * 64 + lane];
        float e0 = as0 + ad; e0 = (e0 > 0.f) ? e0 : 0.2f * e0;
        float e1 = as1 + ad; e1 = (e1 > 0.f) ? e1 : 0.2f * e1;
        float e2 = as2 + ad; e2 = (e2 > 0.f) ? e2 : 0.2f * e2;
        float e3 = as3 + ad; e3 = (e3 > 0.f) ? e3 : 0.2f * e3;
        float em = fmaxf(fmaxf(e0, e1), fmaxf(e2, e3));
        if (__any(em > m + 8.f)) {
            float mn = fmaxf(m, em);
            float sc = __expf(m - mn);
            den *= sc; ax *= sc; ay *= sc; az *= sc; aw *= sc;
            m = mn;
        }
        float p0 = __expf(e0 - m), p1 = __expf(e1 - m), p2 = __expf(e2 - m), p3 = __expf(e3 - m);
        den += (p0 + p1) + (p2 + p3);
        ax += p0 * (float)v0[0] + p1 * (float)v1[0] + p2 * (float)v2[0] + p3 * (float)v3[0];
        ay += p0 * (float)v0[1] + p1 * (float)v1[1] + p2 * (float)v2[1] + p3 * (float)v3[1];
        az += p0 * (float)v0[2] + p1 * (float)v1[2] + p2 * (float)v2[2] + p3 * (float)v3[2];
        aw += p0 * (float)v0[3] + p1 * (float)v1[3] + p2 * (float)v2[3] + p3 * (float)v3[3];
    }
    for (; k < end; ++k) {
        int s = srcs[k];
        float e = aS[(size_t)s * NHEADS + hh] + ad;
        e = (e > 0.f) ? e : 0.2f * e;
        half4 hv = h4p[(size_t)s * 64 + lane];
        if (__any(e > m + 8.f)) {
            float mn = fmaxf(m, e);
            float sc = __expf(m - mn);
            den *= sc; ax *= sc; ay *= sc; az *= sc; aw *= sc;
            m = mn;
        }
        float p = __expf(e - m);
        den += p;
        ax += p * (float)hv[0];
        ay += p * (float)hv[1];
        az += p * (float)hv[2];
        aw += p * (float)hv[3];
    }
    float inv = 1.f / (den + 1e-16f);
    float4 bv = ((const float4*)bias)[lane];
    float o0 = ax * inv + bv.x, o1 = ay * inv + bv.y, o2 = az * inv + bv.z, o3 = aw * inv + bv.w;
    if (ELU) {
        o0 = (o0 > 0.f) ? o0 : expm1f(o0);
        o1 = (o1 > 0.f) ? o1 : expm1f(o1);
        o2 = (o2 > 0.f) ? o2 : expm1f(o2);
        o3 = (o3 > 0.f) ? o3 : expm1f(o3);
    }
    half4 ov;
    ov[0] = (_Float16)o0; ov[1] = (_Float16)o1; ov[2] = (_Float16)o2; ov[3] = (_Float16)o3;
    ((half4*)out)[(size_t)wid * 64 + lane] = ov;
}

// ---------------- layer 3: [256]->[2] matvec + att scalars (wave per node, x fp16) ----------------

__global__ __launch_bounds__(256) void l3_k(const _Float16* __restrict__ x, const float* __restrict__ W3,
                                            const float* __restrict__ att_s, const float* __restrict__ att_d,
                                            float* __restrict__ h3, float* __restrict__ s3,
                                            float* __restrict__ d3, int N) {
    int wid = blockIdx.x * 4 + (threadIdx.x >> 6);
    if (wid >= N) return;
    int lane = threadIdx.x & 63;
    half4 xv = ((const half4*)x)[(size_t)wid * 64 + lane];
    float x0 = (float)xv[0], x1 = (float)xv[1], x2 = (float)xv[2], x3 = (float)xv[3];
    float4 wa = ((const float4*)W3)[lane * 2];
    float4 wb = ((const float4*)W3)[lane * 2 + 1];
    float p0 = x0 * wa.x + x1 * wa.z + x2 * wb.x + x3 * wb.z;
    float p1 = x0 * wa.y + x1 * wa.w + x2 * wb.y + x3 * wb.w;
#pragma unroll
    for (int off = 1; off < 64; off <<= 1) {
        p0 += __shfl_xor(p0, off);
        p1 += __shfl_xor(p1, off);
    }
    if (lane == 0) {
        h3[(size_t)wid * 2] = p0;
        h3[(size_t)wid * 2 + 1] = p1;
        s3[wid] = p0 * att_s[0] + p1 * att_s[1];
        d3[wid] = p0 * att_d[0] + p1 * att_d[1];
    }
}

// ---------------- layer 3 aggregation: 4 lanes per dst node + shuffle merge ----------------

__global__ __launch_bounds__(256) void agg3_k(const float* __restrict__ h3, const float* __restrict__ s3,
                                              const float* __restrict__ d3, const int* __restrict__ indptr,
                                              const int* __restrict__ srcs, const float* __restrict__ b3,
                                              float* __restrict__ out, int N) {
    int t = blockIdx.x * 256 + threadIdx.x;
    int n = t >> 2;
    if (n >= N) return;
    int sub = t & 3;
    float ad = d3[n];
    float m = MNEG, den = 0.f, a0 = 0.f, a1 = 0.f;
    int beg = indptr[n], end = indptr[n + 1];
    for (int k = beg + sub; k < end; k += 4) {
        int s = srcs[k];
        float e = s3[s] + ad;
        e = (e > 0.f) ? e : 0.2f * e;
        if (e > m + 8.f) {
            float mn = fmaxf(m, e);
            float sc = __expf(m - mn);
            den *= sc; a0 *= sc; a1 *= sc;
            m = mn;
        }
        float p = __expf(e - m);
        den += p;
        a0 += p * h3[(size_t)s * 2];
        a1 += p * h3[(size_t)s * 2 + 1];
    }
    // merge 4 per-lane softmax states (butterfly within 4-lane group)
#pragma unroll
    for (int off = 1; off < 4; off <<= 1) {
        float m2 = __shfl_xor(m, off);
        float den2 = __shfl_xor(den, off);
        float a02 = __shfl_xor(a0, off);
        float a12 = __shfl_xor(a1, off);
        float mn = fmaxf(m, m2);
        float sc1 = __expf(m - mn);
        float sc2 = __expf(m2 - mn);
        den = den * sc1 + den2 * sc2;
        a0 = a0 * sc1 + a02 * sc2;
        a1 = a1 * sc1 + a12 * sc2;
        m = mn;
    }
    if (sub == 0) {
        float inv = 1.f / (den + 1e-16f);
        out[(size_t)n * 2]     = a0 * inv + b3[0];
        out[(size_t)n * 2 + 1] = a1 * inv + b3[1];
    }
}

// ---------------- launch ----------------

extern "C" void kernel_launch(void* const* d_in, const int* in_sizes, int n_in,
                              void* d_out, int out_size, void* d_ws, size_t ws_size,
                              hipStream_t stream) {
    const float* x   = (const float*)d_in[0];
    const int*   ei  = (const int*)d_in[1];
    const float* W1  = (const float*)d_in[2];
    const float* as1 = (const float*)d_in[3];
    const float* ad1 = (const float*)d_in[4];
    const float* b1  = (const float*)d_in[5];
    const float* W2  = (const float*)d_in[6];
    const float* as2 = (const float*)d_in[7];
    const float* ad2 = (const float*)d_in[8];
    const float* b2  = (const float*)d_in[9];
    const float* W3  = (const float*)d_in[10];
    const float* at_s3 = (const float*)d_in[11];
    const float* at_d3 = (const float*)d_in[12];
    const float* b3  = (const float*)d_in[13];

    int N = in_sizes[0] / NF;   // 50000
    int E = in_sizes[1] / 2;    // 800000
    const int* esrc = ei;
    const int* edst = ei + E;

    char* w = (char*)d_ws;
    _Float16* hbuf  = (_Float16*)w; w += (size_t)N * NF * 2;
    _Float16* xnext = (_Float16*)w; w += (size_t)N * NF * 2;
    float* aS    = (float*)w; w += (size_t)N * NHEADS * 4;
    float* aD    = (float*)w; w += (size_t)N * NHEADS * 4;
    float* h3    = (float*)w; w += (size_t)N * 2 * 4;
    float* s3    = (float*)w; w += (size_t)N * 4;
    float* d3    = (float*)w; w += (size_t)N * 4;
    int* deg     = (int*)w; w += (size_t)N * 4;
    int* indptr  = (int*)w; w += (size_t)(N + 1) * 4 + 60;
    int* cursor  = (int*)w; w += (size_t)N * 4;
    int* srcs    = (int*)w;

    int nb_n = (N + 255) / 256;
    int nb_e = (E + 255) / 256;
    int nb_w = (N + 3) / 4;
    int nb_g = (N + 255) / 256;
    int nb_a3 = (N * 4 + 255) / 256;

    // CSR build (dst-grouped, incl. self loops)
    deg_init_k<<<nb_n, 256, 0, stream>>>(deg, N);
    deg_count_k<<<nb_e, 256, 0, stream>>>(edst, deg, E);
    scan_k<<<1, 1024, 0, stream>>>(deg, indptr, N);
    fill_self_k<<<nb_n, 256, 0, stream>>>(indptr, cursor, srcs, N);
    fill_edge_k<<<nb_e, 256, 0, stream>>>(esrc, edst, cursor, srcs, E);

    // layer 1
    gemm_mfma_k<1><<<nb_g, 512, 0, stream>>>(x, W1, hbuf, N);
    alpha_k<<<nb_w, 256, 0, stream>>>(hbuf, as1, ad1, aS, aD, N);
    agg_k<true><<<nb_w, 256, 0, stream>>>(hbuf, aS, aD, indptr, srcs, b1, xnext, N);
    // layer 2
    gemm_mfma_k<0><<<nb_g, 512, 0, stream>>>(xnext, W2, hbuf, N);
    alpha_k<<<nb_w, 256, 0, stream>>>(hbuf, as2, ad2, aS, aD, N);
    agg_k<true><<<nb_w, 256, 0, stream>>>(hbuf, aS, aD, indptr, srcs, b2, xnext, N);
    // layer 3
    l3_k<<<nb_w, 256, 0, stream>>>(xnext, W3, at_s3, at_d3, h3, s3, d3, N);
    agg3_k<<<nb_a3, 256, 0, stream>>>(h3, s3, d3, indptr, srcs, b3, (float*)d_out, N);
}

// Round 4
// 342.167 us; speedup vs baseline: 2.0211x; 1.1816x over previous
//
#include <hip/hip_runtime.h>
#include <math.h>

#define NF 256
#define NHEADS 8
#define MNEG -1e30f

typedef _Float16 half8 __attribute__((ext_vector_type(8)));
typedef _Float16 half4 __attribute__((ext_vector_type(4)));
typedef float f32x4 __attribute__((ext_vector_type(4)));

// ---------------- CSR build ----------------

__global__ __launch_bounds__(256) void deg_count_k(const int* __restrict__ dst, int* __restrict__ deg, int E) {
    int e = blockIdx.x * 256 + threadIdx.x;
    if (e < E) atomicAdd(&deg[dst[e]], 1);
}

// phase 1: per-block exclusive scan of deg; indptr[i] = excl-within-block, bsum[b] = block total
__global__ __launch_bounds__(256) void scan1_k(const int* __restrict__ deg, int* __restrict__ indptr,
                                               int* __restrict__ bsum, int n) {
    __shared__ int sh[256];
    int tid = threadIdx.x;
    int i = blockIdx.x * 256 + tid;
    int d = (i < n) ? deg[i] : 0;
    sh[tid] = d;
    __syncthreads();
#pragma unroll
    for (int off = 1; off < 256; off <<= 1) {
        int t = (tid >= off) ? sh[tid - off] : 0;
        __syncthreads();
        sh[tid] += t;
        __syncthreads();
    }
    if (i < n) indptr[i] = sh[tid] - d;
    if (tid == 255) bsum[blockIdx.x] = sh[255];
}

// phase 2: exclusive scan of block sums (nb <= 256)
__global__ __launch_bounds__(256) void scan2_k(int* __restrict__ bsum, int* __restrict__ boff, int nb) {
    __shared__ int sh[256];
    int tid = threadIdx.x;
    int d = (tid < nb) ? bsum[tid] : 0;
    sh[tid] = d;
    __syncthreads();
#pragma unroll
    for (int off = 1; off < 256; off <<= 1) {
        int t = (tid >= off) ? sh[tid - off] : 0;
        __syncthreads();
        sh[tid] += t;
        __syncthreads();
    }
    if (tid < nb) boff[tid] = sh[tid] - d;
}

// phase 3: add block offset + i (self-loops); last element writes indptr[n]
__global__ __launch_bounds__(256) void scan3_k(const int* __restrict__ deg, int* __restrict__ indptr,
                                               const int* __restrict__ boff, int n) {
    int i = blockIdx.x * 256 + threadIdx.x;
    if (i < n) {
        int v = indptr[i] + boff[blockIdx.x] + i;
        indptr[i] = v;
        if (i == n - 1) indptr[n] = v + deg[i] + 1;
    }
}

__global__ __launch_bounds__(256) void fill_self_k(const int* __restrict__ indptr, int* __restrict__ cursor,
                                                   int* __restrict__ srcs, int n) {
    int i = blockIdx.x * 256 + threadIdx.x;
    if (i < n) { int p = indptr[i]; srcs[p] = i; cursor[i] = p + 1; }
}

__global__ __launch_bounds__(256) void fill_edge_k(const int* __restrict__ esrc, const int* __restrict__ edst,
                                                   int* __restrict__ cursor, int* __restrict__ srcs, int E) {
    int e = blockIdx.x * 256 + threadIdx.x;
    if (e < E) {
        int p = atomicAdd(&cursor[edst[e]], 1);
        srcs[p] = esrc[e];
    }
}

// ---------------- MFMA f16 GEMM + fused alpha: C[M,256] = A @ W, aS/aD per head ----------------
// Block: 512 thr = 8 waves (2m x 4n). Block tile 256 rows x 256 cols. Whole W^T in LDS fp16.

template <int AF32>
__global__ __launch_bounds__(512, 2) void gemm_mfma_k(const void* __restrict__ Av, const float* __restrict__ W,
                                                      const float* __restrict__ att_s, const float* __restrict__ att_d,
                                                      _Float16* __restrict__ C, float* __restrict__ aS,
                                                      float* __restrict__ aD, int M) {
    __shared__ __align__(16) _Float16 WT[256][264];  // [col][k], 528B row stride
    int t = threadIdx.x;
    {
        int cq = (t & 7) | ((t >> 6) << 3);  // col-quad 0..63
        int ko = (t >> 3) & 7;               // k-oct
        for (int it = 0; it < 4; ++it) {
            int kb = it * 64 + ko * 8;
            float wv[8][4];
#pragma unroll
            for (int j = 0; j < 8; ++j) {
                float4 v = *(const float4*)&W[(size_t)(kb + j) * 256 + cq * 4];
                wv[j][0] = v.x; wv[j][1] = v.y; wv[j][2] = v.z; wv[j][3] = v.w;
            }
#pragma unroll
            for (int c = 0; c < 4; ++c) {
                half8 p;
#pragma unroll
                for (int j = 0; j < 8; ++j) p[j] = (_Float16)wv[j][c];
                *(half8*)&WT[cq * 4 + c][kb] = p;
            }
        }
    }
    __syncthreads();

    int wave = t >> 6, lane = t & 63;
    int wm = wave >> 2, wn = wave & 3;   // 2 x 4 wave grid
    int lr = lane & 15, lg = lane >> 4;
    int r0 = blockIdx.x * 256 + wm * 128;
    int c0 = wn * 64;
    const float* Af = (const float*)Av;
    const _Float16* Ah = (const _Float16*)Av;

    f32x4 acc[8][4];
#pragma unroll
    for (int mr = 0; mr < 8; ++mr)
#pragma unroll
        for (int nr = 0; nr < 4; ++nr) acc[mr][nr] = (f32x4){0.f, 0.f, 0.f, 0.f};

    for (int ks = 0; ks < 8; ++ks) {
        int k0 = ks * 32;
        half8 a[8];
#pragma unroll
        for (int mr = 0; mr < 8; ++mr) {
            int row = r0 + mr * 16 + lr;
            row = row < M ? row : M - 1;
            if (AF32) {
                const float* p = Af + (size_t)row * 256 + k0 + lg * 8;
                float4 x0 = *(const float4*)p;
                float4 x1 = *(const float4*)(p + 4);
                half8 av;
                av[0] = (_Float16)x0.x; av[1] = (_Float16)x0.y; av[2] = (_Float16)x0.z; av[3] = (_Float16)x0.w;
                av[4] = (_Float16)x1.x; av[5] = (_Float16)x1.y; av[6] = (_Float16)x1.z; av[7] = (_Float16)x1.w;
                a[mr] = av;
            } else {
                a[mr] = *(const half8*)(Ah + (size_t)row * 256 + k0 + lg * 8);
            }
        }
        half8 b[4];
#pragma unroll
        for (int nr = 0; nr < 4; ++nr)
            b[nr] = *(const half8*)&WT[c0 + nr * 16 + lr][k0 + lg * 8];
#pragma unroll
        for (int mr = 0; mr < 8; ++mr)
#pragma unroll
            for (int nr = 0; nr < 4; ++nr)
                acc[mr][nr] = __builtin_amdgcn_mfma_f32_16x16x32_f16(a[mr], b[nr], acc[mr][nr], 0, 0, 0);
    }

    // att coefficients for this wave's two heads
    int h0 = wn * 2, h1 = wn * 2 + 1;
    float as_c0 = att_s[h0 * 32 + lr],      as_c1 = att_s[h0 * 32 + 16 + lr];
    float as_c2 = att_s[h1 * 32 + lr],      as_c3 = att_s[h1 * 32 + 16 + lr];
    float ad_c0 = att_d[h0 * 32 + lr],      ad_c1 = att_d[h0 * 32 + 16 + lr];
    float ad_c2 = att_d[h1 * 32 + lr],      ad_c3 = att_d[h1 * 32 + 16 + lr];

#pragma unroll
    for (int mr = 0; mr < 8; ++mr) {
        int rbase = r0 + mr * 16 + lg * 4;
#pragma unroll
        for (int j = 0; j < 4; ++j) {
            int row = rbase + j;
            // alpha partials for this row (all 16 lanes of the lg-group share `row`)
            float ps0 = acc[mr][0][j] * as_c0 + acc[mr][1][j] * as_c1;
            float ps1 = acc[mr][2][j] * as_c2 + acc[mr][3][j] * as_c3;
            float pd0 = acc[mr][0][j] * ad_c0 + acc[mr][1][j] * ad_c1;
            float pd1 = acc[mr][2][j] * ad_c2 + acc[mr][3][j] * ad_c3;
#pragma unroll
            for (int o = 1; o < 16; o <<= 1) {
                ps0 += __shfl_xor(ps0, o);
                ps1 += __shfl_xor(ps1, o);
                pd0 += __shfl_xor(pd0, o);
                pd1 += __shfl_xor(pd1, o);
            }
            if (row < M) {
#pragma unroll
                for (int nr = 0; nr < 4; ++nr)
                    C[(size_t)row * 256 + c0 + nr * 16 + lr] = (_Float16)acc[mr][nr][j];
                if (lr == 0) {
                    aS[(size_t)row * NHEADS + h0] = ps0;
                    aS[(size_t)row * NHEADS + h1] = ps1;
                    aD[(size_t)row * NHEADS + h0] = pd0;
                    aD[(size_t)row * NHEADS + h1] = pd1;
                }
            }
        }
    }
}

// ---------------- aggregation: wave per dst, 8-edge unroll, deferred-max online softmax ----------------

template <bool ELU>
__global__ __launch_bounds__(256) void agg_k(const _Float16* __restrict__ h, const float* __restrict__ aS,
                                             const float* __restrict__ aD, const int* __restrict__ indptr,
                                             const int* __restrict__ srcs, const float* __restrict__ bias,
                                             _Float16* __restrict__ out, int N) {
    int wid = blockIdx.x * 4 + (threadIdx.x >> 6);
    if (wid >= N) return;
    int lane = threadIdx.x & 63;
    int hh = lane >> 3;
    float ad = aD[(size_t)wid * NHEADS + hh];
    int beg = indptr[wid], end = indptr[wid + 1];
    const half4* h4p = (const half4*)h;
    float m = MNEG, den = 0.f;
    float ax = 0.f, ay = 0.f, az = 0.f, aw = 0.f;
    int k = beg;
    for (; k + 8 <= end; k += 8) {
        int s[8];
        float as[8], e[8], p[8];
        half4 v[8];
#pragma unroll
        for (int j = 0; j < 8; ++j) s[j] = srcs[k + j];
#pragma unroll
        for (int j = 0; j < 8; ++j) as[j] = aS[(size_t)s[j] * NHEADS + hh];
#pragma unroll
        for (int j = 0; j < 8; ++j) v[j] = h4p[(size_t)s[j] * 64 + lane];
#pragma unroll
        for (int j = 0; j < 8; ++j) { e[j] = as[j] + ad; e[j] = (e[j] > 0.f) ? e[j] : 0.2f * e[j]; }
        float em = fmaxf(fmaxf(fmaxf(e[0], e[1]), fmaxf(e[2], e[3])),
                         fmaxf(fmaxf(e[4], e[5]), fmaxf(e[6], e[7])));
        if (__any(em > m + 8.f)) {
            float mn = fmaxf(m, em);
            float sc = __expf(m - mn);
            den *= sc; ax *= sc; ay *= sc; az *= sc; aw *= sc;
            m = mn;
        }
#pragma unroll
        for (int j = 0; j < 8; ++j) p[j] = __expf(e[j] - m);
#pragma unroll
        for (int j = 0; j < 8; ++j) {
            den += p[j];
            ax += p[j] * (float)v[j][0];
            ay += p[j] * (float)v[j][1];
            az += p[j] * (float)v[j][2];
            aw += p[j] * (float)v[j][3];
        }
    }
    for (; k < end; ++k) {
        int s = srcs[k];
        float e = aS[(size_t)s * NHEADS + hh] + ad;
        e = (e > 0.f) ? e : 0.2f * e;
        half4 hv = h4p[(size_t)s * 64 + lane];
        if (__any(e > m + 8.f)) {
            float mn = fmaxf(m, e);
            float sc = __expf(m - mn);
            den *= sc; ax *= sc; ay *= sc; az *= sc; aw *= sc;
            m = mn;
        }
        float p = __expf(e - m);
        den += p;
        ax += p * (float)hv[0];
        ay += p * (float)hv[1];
        az += p * (float)hv[2];
        aw += p * (float)hv[3];
    }
    float inv = 1.f / (den + 1e-16f);
    float4 bv = ((const float4*)bias)[lane];
    float o0 = ax * inv + bv.x, o1 = ay * inv + bv.y, o2 = az * inv + bv.z, o3 = aw * inv + bv.w;
    if (ELU) {
        o0 = (o0 > 0.f) ? o0 : expm1f(o0);
        o1 = (o1 > 0.f) ? o1 : expm1f(o1);
        o2 = (o2 > 0.f) ? o2 : expm1f(o2);
        o3 = (o3 > 0.f) ? o3 : expm1f(o3);
    }
    half4 ov;
    ov[0] = (_Float16)o0; ov[1] = (_Float16)o1; ov[2] = (_Float16)o2; ov[3] = (_Float16)o3;
    ((half4*)out)[(size_t)wid * 64 + lane] = ov;
}

// ---------------- layer 3: [256]->[2] matvec + att scalars (wave per node, x fp16) ----------------

__global__ __launch_bounds__(256) void l3_k(const _Float16* __restrict__ x, const float* __restrict__ W3,
                                            const float* __restrict__ att_s, const float* __restrict__ att_d,
                                            float* __restrict__ h3, float* __restrict__ s3,
                                            float* __restrict__ d3, int N) {
    int wid = blockIdx.x * 4 + (threadIdx.x >> 6);
    if (wid >= N) return;
    int lane = threadIdx.x & 63;
    half4 xv = ((const half4*)x)[(size_t)wid * 64 + lane];
    float x0 = (float)xv[0], x1 = (float)xv[1], x2 = (float)xv[2], x3 = (float)xv[3];
    float4 wa = ((const float4*)W3)[lane * 2];
    float4 wb = ((const float4*)W3)[lane * 2 + 1];
    float p0 = x0 * wa.x + x1 * wa.z + x2 * wb.x + x3 * wb.z;
    float p1 = x0 * wa.y + x1 * wa.w + x2 * wb.y + x3 * wb.w;
#pragma unroll
    for (int off = 1; off < 64; off <<= 1) {
        p0 += __shfl_xor(p0, off);
        p1 += __shfl_xor(p1, off);
    }
    if (lane == 0) {
        h3[(size_t)wid * 2] = p0;
        h3[(size_t)wid * 2 + 1] = p1;
        s3[wid] = p0 * att_s[0] + p1 * att_s[1];
        d3[wid] = p0 * att_d[0] + p1 * att_d[1];
    }
}

// ---------------- layer 3 aggregation: 4 lanes per dst node + shuffle merge ----------------

__global__ __launch_bounds__(256) void agg3_k(const float* __restrict__ h3, const float* __restrict__ s3,
                                              const float* __restrict__ d3, const int* __restrict__ indptr,
                                              const int* __restrict__ srcs, const float* __restrict__ b3,
                                              float* __restrict__ out, int N) {
    int t = blockIdx.x * 256 + threadIdx.x;
    int n = t >> 2;
    if (n >= N) return;
    int sub = t & 3;
    float ad = d3[n];
    float m = MNEG, den = 0.f, a0 = 0.f, a1 = 0.f;
    int beg = indptr[n], end = indptr[n + 1];
    for (int k = beg + sub; k < end; k += 4) {
        int s = srcs[k];
        float e = s3[s] + ad;
        e = (e > 0.f) ? e : 0.2f * e;
        if (e > m + 8.f) {
            float mn = fmaxf(m, e);
            float sc = __expf(m - mn);
            den *= sc; a0 *= sc; a1 *= sc;
            m = mn;
        }
        float p = __expf(e - m);
        den += p;
        a0 += p * h3[(size_t)s * 2];
        a1 += p * h3[(size_t)s * 2 + 1];
    }
#pragma unroll
    for (int off = 1; off < 4; off <<= 1) {
        float m2 = __shfl_xor(m, off);
        float den2 = __shfl_xor(den, off);
        float a02 = __shfl_xor(a0, off);
        float a12 = __shfl_xor(a1, off);
        float mn = fmaxf(m, m2);
        float sc1 = __expf(m - mn);
        float sc2 = __expf(m2 - mn);
        den = den * sc1 + den2 * sc2;
        a0 = a0 * sc1 + a02 * sc2;
        a1 = a1 * sc1 + a12 * sc2;
        m = mn;
    }
    if (sub == 0) {
        float inv = 1.f / (den + 1e-16f);
        out[(size_t)n * 2]     = a0 * inv + b3[0];
        out[(size_t)n * 2 + 1] = a1 * inv + b3[1];
    }
}

// ---------------- launch ----------------

extern "C" void kernel_launch(void* const* d_in, const int* in_sizes, int n_in,
                              void* d_out, int out_size, void* d_ws, size_t ws_size,
                              hipStream_t stream) {
    const float* x   = (const float*)d_in[0];
    const int*   ei  = (const int*)d_in[1];
    const float* W1  = (const float*)d_in[2];
    const float* as1 = (const float*)d_in[3];
    const float* ad1 = (const float*)d_in[4];
    const float* b1  = (const float*)d_in[5];
    const float* W2  = (const float*)d_in[6];
    const float* as2 = (const float*)d_in[7];
    const float* ad2 = (const float*)d_in[8];
    const float* b2  = (const float*)d_in[9];
    const float* W3  = (const float*)d_in[10];
    const float* at_s3 = (const float*)d_in[11];
    const float* at_d3 = (const float*)d_in[12];
    const float* b3  = (const float*)d_in[13];

    int N = in_sizes[0] / NF;   // 50000
    int E = in_sizes[1] / 2;    // 800000
    const int* esrc = ei;
    const int* edst = ei + E;

    char* w = (char*)d_ws;
    _Float16* hbuf  = (_Float16*)w; w += (size_t)N * NF * 2;
    _Float16* xnext = (_Float16*)w; w += (size_t)N * NF * 2;
    float* aS    = (float*)w; w += (size_t)N * NHEADS * 4;
    float* aD    = (float*)w; w += (size_t)N * NHEADS * 4;
    float* h3    = (float*)w; w += (size_t)N * 2 * 4;
    float* s3    = (float*)w; w += (size_t)N * 4;
    float* d3    = (float*)w; w += (size_t)N * 4;
    int* deg     = (int*)w; w += (size_t)N * 4;
    int* indptr  = (int*)w; w += (size_t)(N + 1) * 4 + 60;
    int* cursor  = (int*)w; w += (size_t)N * 4;
    int* bsum    = (int*)w; w += 256 * 4;
    int* boff    = (int*)w; w += 256 * 4;
    int* srcs    = (int*)w;

    int nb_n = (N + 255) / 256;   // 196
    int nb_e = (E + 255) / 256;   // 3125
    int nb_w = (N + 3) / 4;
    int nb_g = (N + 255) / 256;
    int nb_a3 = (N * 4 + 255) / 256;

    // CSR build (dst-grouped, incl. self loops folded in as +i)
    hipMemsetAsync(deg, 0, (size_t)N * 4, stream);
    deg_count_k<<<nb_e, 256, 0, stream>>>(edst, deg, E);
    scan1_k<<<nb_n, 256, 0, stream>>>(deg, indptr, bsum, N);
    scan2_k<<<1, 256, 0, stream>>>(bsum, boff, nb_n);
    scan3_k<<<nb_n, 256, 0, stream>>>(deg, indptr, boff, N);
    fill_self_k<<<nb_n, 256, 0, stream>>>(indptr, cursor, srcs, N);
    fill_edge_k<<<nb_e, 256, 0, stream>>>(esrc, edst, cursor, srcs, E);

    // layer 1
    gemm_mfma_k<1><<<nb_g, 512, 0, stream>>>(x, W1, as1, ad1, hbuf, aS, aD, N);
    agg_k<true><<<nb_w, 256, 0, stream>>>(hbuf, aS, aD, indptr, srcs, b1, xnext, N);
    // layer 2
    gemm_mfma_k<0><<<nb_g, 512, 0, stream>>>(xnext, W2, as2, ad2, hbuf, aS, aD, N);
    agg_k<true><<<nb_w, 256, 0, stream>>>(hbuf, aS, aD, indptr, srcs, b2, xnext, N);
    // layer 3
    l3_k<<<nb_w, 256, 0, stream>>>(xnext, W3, at_s3, at_d3, h3, s3, d3, N);
    agg3_k<<<nb_a3, 256, 0, stream>>>(h3, s3, d3, indptr, srcs, b3, (float*)d_out, N);
}

// Round 5
// 326.864 us; speedup vs baseline: 2.1157x; 1.0468x over previous
//
#include <hip/hip_runtime.h>
#include <math.h>

#define NF 256
#define NHEADS 8
#define MNEG -1e30f

typedef _Float16 half8 __attribute__((ext_vector_type(8)));
typedef _Float16 half4 __attribute__((ext_vector_type(4)));
typedef float f32x4 __attribute__((ext_vector_type(4)));

// ---------------- CSR build ----------------

__global__ __launch_bounds__(256) void deg_count_k(const int* __restrict__ dst, int* __restrict__ deg, int E) {
    int e = blockIdx.x * 256 + threadIdx.x;
    if (e < E) atomicAdd(&deg[dst[e]], 1);
}

__global__ __launch_bounds__(256) void scan1_k(const int* __restrict__ deg, int* __restrict__ indptr,
                                               int* __restrict__ bsum, int n) {
    __shared__ int sh[256];
    int tid = threadIdx.x;
    int i = blockIdx.x * 256 + tid;
    int d = (i < n) ? deg[i] : 0;
    sh[tid] = d;
    __syncthreads();
#pragma unroll
    for (int off = 1; off < 256; off <<= 1) {
        int t = (tid >= off) ? sh[tid - off] : 0;
        __syncthreads();
        sh[tid] += t;
        __syncthreads();
    }
    if (i < n) indptr[i] = sh[tid] - d;
    if (tid == 255) bsum[blockIdx.x] = sh[255];
}

__global__ __launch_bounds__(256) void scan2_k(int* __restrict__ bsum, int* __restrict__ boff, int nb) {
    __shared__ int sh[256];
    int tid = threadIdx.x;
    int d = (tid < nb) ? bsum[tid] : 0;
    sh[tid] = d;
    __syncthreads();
#pragma unroll
    for (int off = 1; off < 256; off <<= 1) {
        int t = (tid >= off) ? sh[tid - off] : 0;
        __syncthreads();
        sh[tid] += t;
        __syncthreads();
    }
    if (tid < nb) boff[tid] = sh[tid] - d;
}

// phase 3 + fill_self: finalize indptr (block offset + i self-loops), seed srcs/cursor
__global__ __launch_bounds__(256) void scan3_k(const int* __restrict__ deg, int* __restrict__ indptr,
                                               const int* __restrict__ boff, int* __restrict__ cursor,
                                               int* __restrict__ srcs, int n) {
    int i = blockIdx.x * 256 + threadIdx.x;
    if (i < n) {
        int v = indptr[i] + boff[blockIdx.x] + i;
        indptr[i] = v;
        srcs[v] = i;           // self loop first
        cursor[i] = v + 1;
        if (i == n - 1) indptr[n] = v + deg[i] + 1;
    }
}

__global__ __launch_bounds__(256) void fill_edge_k(const int* __restrict__ esrc, const int* __restrict__ edst,
                                                   int* __restrict__ cursor, int* __restrict__ srcs, int E) {
    int e = blockIdx.x * 256 + threadIdx.x;
    if (e < E) {
        int p = atomicAdd(&cursor[edst[e]], 1);
        srcs[p] = esrc[e];
    }
}

// ---------------- W pre-transpose to fp16 [col][k] ----------------

__global__ __launch_bounds__(256) void prep_w_k(const float* __restrict__ W, _Float16* __restrict__ WTh) {
    int tid = blockIdx.x * 256 + threadIdx.x;   // 65536
    int k = tid >> 8, c = tid & 255;            // coalesced read of W[k][*]
    WTh[(size_t)c * 256 + k] = (_Float16)W[(size_t)k * 256 + c];
}

// ---------------- MFMA f16 GEMM + fused alpha ----------------
// Block: 512 thr = 8 waves (2m x 4n), tile 256x256, W^T fp16 staged to LDS.

template <int AF32>
__global__ __launch_bounds__(512, 2) void gemm_mfma_k(const void* __restrict__ Av, const _Float16* __restrict__ WTh,
                                                      const float* __restrict__ att_s, const float* __restrict__ att_d,
                                                      _Float16* __restrict__ C, float* __restrict__ aS,
                                                      float* __restrict__ aD, int M) {
    __shared__ __align__(16) _Float16 WT[256][264];  // [col][k], 528B row stride
    int t = threadIdx.x;
#pragma unroll
    for (int it = 0; it < 16; ++it) {
        int col = it * 16 + (t >> 5);
        int kc = (t & 31) * 8;
        *(half8*)&WT[col][kc] = *(const half8*)&WTh[(size_t)col * 256 + kc];
    }
    __syncthreads();

    int wave = t >> 6, lane = t & 63;
    int wm = wave >> 2, wn = wave & 3;
    int lr = lane & 15, lg = lane >> 4;
    int r0 = blockIdx.x * 256 + wm * 128;
    int c0 = wn * 64;
    const float* Af = (const float*)Av;
    const _Float16* Ah = (const _Float16*)Av;

    f32x4 acc[8][4];
#pragma unroll
    for (int mr = 0; mr < 8; ++mr)
#pragma unroll
        for (int nr = 0; nr < 4; ++nr) acc[mr][nr] = (f32x4){0.f, 0.f, 0.f, 0.f};

    for (int ks = 0; ks < 8; ++ks) {
        int k0 = ks * 32;
        half8 a[8];
#pragma unroll
        for (int mr = 0; mr < 8; ++mr) {
            int row = r0 + mr * 16 + lr;
            row = row < M ? row : M - 1;
            if (AF32) {
                const float* p = Af + (size_t)row * 256 + k0 + lg * 8;
                float4 x0 = *(const float4*)p;
                float4 x1 = *(const float4*)(p + 4);
                half8 av;
                av[0] = (_Float16)x0.x; av[1] = (_Float16)x0.y; av[2] = (_Float16)x0.z; av[3] = (_Float16)x0.w;
                av[4] = (_Float16)x1.x; av[5] = (_Float16)x1.y; av[6] = (_Float16)x1.z; av[7] = (_Float16)x1.w;
                a[mr] = av;
            } else {
                a[mr] = *(const half8*)(Ah + (size_t)row * 256 + k0 + lg * 8);
            }
        }
        half8 b[4];
#pragma unroll
        for (int nr = 0; nr < 4; ++nr)
            b[nr] = *(const half8*)&WT[c0 + nr * 16 + lr][k0 + lg * 8];
#pragma unroll
        for (int mr = 0; mr < 8; ++mr)
#pragma unroll
            for (int nr = 0; nr < 4; ++nr)
                acc[mr][nr] = __builtin_amdgcn_mfma_f32_16x16x32_f16(a[mr], b[nr], acc[mr][nr], 0, 0, 0);
    }

    int h0 = wn * 2, h1 = wn * 2 + 1;
    float as_c0 = att_s[h0 * 32 + lr],      as_c1 = att_s[h0 * 32 + 16 + lr];
    float as_c2 = att_s[h1 * 32 + lr],      as_c3 = att_s[h1 * 32 + 16 + lr];
    float ad_c0 = att_d[h0 * 32 + lr],      ad_c1 = att_d[h0 * 32 + 16 + lr];
    float ad_c2 = att_d[h1 * 32 + lr],      ad_c3 = att_d[h1 * 32 + 16 + lr];

#pragma unroll
    for (int mr = 0; mr < 8; ++mr) {
        int rbase = r0 + mr * 16 + lg * 4;
#pragma unroll
        for (int j = 0; j < 4; ++j) {
            int row = rbase + j;
            float ps0 = acc[mr][0][j] * as_c0 + acc[mr][1][j] * as_c1;
            float ps1 = acc[mr][2][j] * as_c2 + acc[mr][3][j] * as_c3;
            float pd0 = acc[mr][0][j] * ad_c0 + acc[mr][1][j] * ad_c1;
            float pd1 = acc[mr][2][j] * ad_c2 + acc[mr][3][j] * ad_c3;
#pragma unroll
            for (int o = 1; o < 16; o <<= 1) {
                ps0 += __shfl_xor(ps0, o);
                ps1 += __shfl_xor(ps1, o);
                pd0 += __shfl_xor(pd0, o);
                pd1 += __shfl_xor(pd1, o);
            }
            if (row < M) {
#pragma unroll
                for (int nr = 0; nr < 4; ++nr)
                    C[(size_t)row * 256 + c0 + nr * 16 + lr] = (_Float16)acc[mr][nr][j];
                if (lr == 0) {
                    aS[(size_t)row * NHEADS + h0] = ps0;
                    aS[(size_t)row * NHEADS + h1] = ps1;
                    aD[(size_t)row * NHEADS + h0] = pd0;
                    aD[(size_t)row * NHEADS + h1] = pd1;
                }
            }
        }
    }
}

// ---------------- aggregation: wave per dst, 2 edges per iter (half8 lanes), online softmax ----------------
// MODE 0: write fp16 row (layer1). MODE 1: fuse layer-3 matvec -> h3/s3/d3 (layer2, no row write).

template <int MODE>
__global__ __launch_bounds__(256) void agg_k(const _Float16* __restrict__ h, const float* __restrict__ aS,
                                             const float* __restrict__ aD, const int* __restrict__ indptr,
                                             const int* __restrict__ srcs, const float* __restrict__ bias,
                                             _Float16* __restrict__ out,
                                             const float* __restrict__ W3, const float* __restrict__ as3,
                                             const float* __restrict__ ad3, float* __restrict__ h3,
                                             float* __restrict__ s3, float* __restrict__ d3, int N) {
    int wid = blockIdx.x * 4 + (threadIdx.x >> 6);
    if (wid >= N) return;
    int lane = threadIdx.x & 63;
    int hf = lane >> 5;          // which edge of a pair
    int cl = lane & 31;          // channel-lane: 8 ch at cl*8
    int hh = cl >> 2;            // head
    float ad = aD[(size_t)wid * NHEADS + hh];
    int beg = indptr[wid], end = indptr[wid + 1];
    const half8* h8p = (const half8*)h;
    float m = MNEG, den = 0.f;
    float a0 = 0, a1 = 0, a2 = 0, a3 = 0, a4 = 0, a5 = 0, a6 = 0, a7 = 0;
    int k = beg;
    for (; k + 8 <= end; k += 8) {
        int s[4]; float as[4]; half8 v[4]; float e[4], p[4];
#pragma unroll
        for (int j = 0; j < 4; ++j) s[j] = srcs[k + 2 * j + hf];
#pragma unroll
        for (int j = 0; j < 4; ++j) as[j] = aS[(size_t)s[j] * NHEADS + hh];
#pragma unroll
        for (int j = 0; j < 4; ++j) v[j] = h8p[(size_t)s[j] * 32 + cl];
#pragma unroll
        for (int j = 0; j < 4; ++j) { e[j] = as[j] + ad; e[j] = (e[j] > 0.f) ? e[j] : 0.2f * e[j]; }
        float em = fmaxf(fmaxf(e[0], e[1]), fmaxf(e[2], e[3]));
        if (__any(em > m + 8.f)) {
            float mn = fmaxf(m, em);
            float sc = __expf(m - mn);
            den *= sc; a0 *= sc; a1 *= sc; a2 *= sc; a3 *= sc; a4 *= sc; a5 *= sc; a6 *= sc; a7 *= sc;
            m = mn;
        }
#pragma unroll
        for (int j = 0; j < 4; ++j) p[j] = __expf(e[j] - m);
#pragma unroll
        for (int j = 0; j < 4; ++j) {
            den += p[j];
            a0 += p[j] * (float)v[j][0]; a1 += p[j] * (float)v[j][1];
            a2 += p[j] * (float)v[j][2]; a3 += p[j] * (float)v[j][3];
            a4 += p[j] * (float)v[j][4]; a5 += p[j] * (float)v[j][5];
            a6 += p[j] * (float)v[j][6]; a7 += p[j] * (float)v[j][7];
        }
    }
    for (; k + 2 <= end; k += 2) {
        int s = srcs[k + hf];
        float as = aS[(size_t)s * NHEADS + hh];
        half8 v = h8p[(size_t)s * 32 + cl];
        float e = as + ad; e = (e > 0.f) ? e : 0.2f * e;
        if (__any(e > m + 8.f)) {
            float mn = fmaxf(m, e);
            float sc = __expf(m - mn);
            den *= sc; a0 *= sc; a1 *= sc; a2 *= sc; a3 *= sc; a4 *= sc; a5 *= sc; a6 *= sc; a7 *= sc;
            m = mn;
        }
        float p = __expf(e - m);
        den += p;
        a0 += p * (float)v[0]; a1 += p * (float)v[1]; a2 += p * (float)v[2]; a3 += p * (float)v[3];
        a4 += p * (float)v[4]; a5 += p * (float)v[5]; a6 += p * (float)v[6]; a7 += p * (float)v[7];
    }
    if (k < end) {  // odd tail: lanes hf==0 only
        int s = srcs[k];
        float e = aS[(size_t)s * NHEADS + hh] + ad;
        e = (e > 0.f) ? e : 0.2f * e;
        half8 v = h8p[(size_t)s * 32 + cl];
        float eg = (hf == 0) ? e : MNEG;
        if (__any(eg > m + 8.f)) {
            float mn = fmaxf(m, eg);
            float sc = __expf(m - mn);
            den *= sc; a0 *= sc; a1 *= sc; a2 *= sc; a3 *= sc; a4 *= sc; a5 *= sc; a6 *= sc; a7 *= sc;
            m = mn;
        }
        float p = (hf == 0) ? __expf(e - m) : 0.f;
        den += p;
        a0 += p * (float)v[0]; a1 += p * (float)v[1]; a2 += p * (float)v[2]; a3 += p * (float)v[3];
        a4 += p * (float)v[4]; a5 += p * (float)v[5]; a6 += p * (float)v[6]; a7 += p * (float)v[7];
    }
    // merge the two half-states (lane l <-> l+32, same channels/head)
    {
        float m2 = __shfl_xor(m, 32);
        float den2 = __shfl_xor(den, 32);
        float mn = fmaxf(m, m2);
        float sc1 = __expf(m - mn), sc2 = __expf(m2 - mn);
        den = den * sc1 + den2 * sc2;
        a0 = a0 * sc1 + __shfl_xor(a0, 32) * sc2;
        a1 = a1 * sc1 + __shfl_xor(a1, 32) * sc2;
        a2 = a2 * sc1 + __shfl_xor(a2, 32) * sc2;
        a3 = a3 * sc1 + __shfl_xor(a3, 32) * sc2;
        a4 = a4 * sc1 + __shfl_xor(a4, 32) * sc2;
        a5 = a5 * sc1 + __shfl_xor(a5, 32) * sc2;
        a6 = a6 * sc1 + __shfl_xor(a6, 32) * sc2;
        a7 = a7 * sc1 + __shfl_xor(a7, 32) * sc2;
    }
    float inv = 1.f / (den + 1e-16f);
    float4 bv0 = *(const float4*)&bias[cl * 8];
    float4 bv1 = *(const float4*)&bias[cl * 8 + 4];
    float o[8];
    o[0] = a0 * inv + bv0.x; o[1] = a1 * inv + bv0.y; o[2] = a2 * inv + bv0.z; o[3] = a3 * inv + bv0.w;
    o[4] = a4 * inv + bv1.x; o[5] = a5 * inv + bv1.y; o[6] = a6 * inv + bv1.z; o[7] = a7 * inv + bv1.w;
#pragma unroll
    for (int c = 0; c < 8; ++c) o[c] = (o[c] > 0.f) ? o[c] : expm1f(o[c]);  // ELU (both layers)

    if (MODE == 0) {
        if (hf == 0) {
            half8 ov;
#pragma unroll
            for (int c = 0; c < 8; ++c) ov[c] = (_Float16)o[c];
            ((half8*)out)[(size_t)wid * 32 + cl] = ov;
        }
    } else {
        // fused layer-3 matvec: rows cl*8..cl*8+7 of W3[256][2]
        const float4* W34 = (const float4*)W3;
        float p0 = 0.f, p1 = 0.f;
#pragma unroll
        for (int q = 0; q < 4; ++q) {
            float4 w = W34[cl * 4 + q];
            p0 += o[2 * q] * w.x + o[2 * q + 1] * w.z;
            p1 += o[2 * q] * w.y + o[2 * q + 1] * w.w;
        }
#pragma unroll
        for (int off = 1; off < 32; off <<= 1) {
            p0 += __shfl_xor(p0, off);
            p1 += __shfl_xor(p1, off);
        }
        if (lane == 0) {
            h3[(size_t)wid * 2] = p0;
            h3[(size_t)wid * 2 + 1] = p1;
            s3[wid] = p0 * as3[0] + p1 * as3[1];
            d3[wid] = p0 * ad3[0] + p1 * ad3[1];
        }
    }
}

// ---------------- layer 3 aggregation: 4 lanes per dst node + shuffle merge ----------------

__global__ __launch_bounds__(256) void agg3_k(const float* __restrict__ h3, const float* __restrict__ s3,
                                              const float* __restrict__ d3, const int* __restrict__ indptr,
                                              const int* __restrict__ srcs, const float* __restrict__ b3,
                                              float* __restrict__ out, int N) {
    int t = blockIdx.x * 256 + threadIdx.x;
    int n = t >> 2;
    if (n >= N) return;
    int sub = t & 3;
    float ad = d3[n];
    float m = MNEG, den = 0.f, a0 = 0.f, a1 = 0.f;
    int beg = indptr[n], end = indptr[n + 1];
    for (int k = beg + sub; k < end; k += 4) {
        int s = srcs[k];
        float e = s3[s] + ad;
        e = (e > 0.f) ? e : 0.2f * e;
        if (e > m + 8.f) {
            float mn = fmaxf(m, e);
            float sc = __expf(m - mn);
            den *= sc; a0 *= sc; a1 *= sc;
            m = mn;
        }
        float p = __expf(e - m);
        den += p;
        a0 += p * h3[(size_t)s * 2];
        a1 += p * h3[(size_t)s * 2 + 1];
    }
#pragma unroll
    for (int off = 1; off < 4; off <<= 1) {
        float m2 = __shfl_xor(m, off);
        float den2 = __shfl_xor(den, off);
        float a02 = __shfl_xor(a0, off);
        float a12 = __shfl_xor(a1, off);
        float mn = fmaxf(m, m2);
        float sc1 = __expf(m - mn);
        float sc2 = __expf(m2 - mn);
        den = den * sc1 + den2 * sc2;
        a0 = a0 * sc1 + a02 * sc2;
        a1 = a1 * sc1 + a12 * sc2;
        m = mn;
    }
    if (sub == 0) {
        float inv = 1.f / (den + 1e-16f);
        out[(size_t)n * 2]     = a0 * inv + b3[0];
        out[(size_t)n * 2 + 1] = a1 * inv + b3[1];
    }
}

// ---------------- launch ----------------

extern "C" void kernel_launch(void* const* d_in, const int* in_sizes, int n_in,
                              void* d_out, int out_size, void* d_ws, size_t ws_size,
                              hipStream_t stream) {
    const float* x   = (const float*)d_in[0];
    const int*   ei  = (const int*)d_in[1];
    const float* W1  = (const float*)d_in[2];
    const float* as1 = (const float*)d_in[3];
    const float* ad1 = (const float*)d_in[4];
    const float* b1  = (const float*)d_in[5];
    const float* W2  = (const float*)d_in[6];
    const float* as2 = (const float*)d_in[7];
    const float* ad2 = (const float*)d_in[8];
    const float* b2  = (const float*)d_in[9];
    const float* W3  = (const float*)d_in[10];
    const float* at_s3 = (const float*)d_in[11];
    const float* at_d3 = (const float*)d_in[12];
    const float* b3  = (const float*)d_in[13];

    int N = in_sizes[0] / NF;   // 50000
    int E = in_sizes[1] / 2;    // 800000
    const int* esrc = ei;
    const int* edst = ei + E;

    char* w = (char*)d_ws;
    _Float16* hbuf  = (_Float16*)w; w += (size_t)N * NF * 2;
    _Float16* xnext = (_Float16*)w; w += (size_t)N * NF * 2;
    float* aS    = (float*)w; w += (size_t)N * NHEADS * 4;
    float* aD    = (float*)w; w += (size_t)N * NHEADS * 4;
    float* h3    = (float*)w; w += (size_t)N * 2 * 4;
    float* s3    = (float*)w; w += (size_t)N * 4;
    float* d3    = (float*)w; w += (size_t)N * 4;
    int* deg     = (int*)w; w += (size_t)N * 4;
    int* indptr  = (int*)w; w += (size_t)(N + 1) * 4 + 60;
    int* cursor  = (int*)w; w += (size_t)N * 4;
    int* bsum    = (int*)w; w += 256 * 4;
    int* boff    = (int*)w; w += 256 * 4;
    _Float16* WTh1 = (_Float16*)w; w += (size_t)256 * 256 * 2;
    _Float16* WTh2 = (_Float16*)w; w += (size_t)256 * 256 * 2;
    int* srcs    = (int*)w;

    int nb_n = (N + 255) / 256;   // 196
    int nb_e = (E + 255) / 256;   // 3125
    int nb_w = (N + 3) / 4;
    int nb_g = (N + 255) / 256;
    int nb_a3 = (N * 4 + 255) / 256;

    // CSR build (dst-grouped, self loops folded in)
    hipMemsetAsync(deg, 0, (size_t)N * 4, stream);
    deg_count_k<<<nb_e, 256, 0, stream>>>(edst, deg, E);
    scan1_k<<<nb_n, 256, 0, stream>>>(deg, indptr, bsum, N);
    scan2_k<<<1, 256, 0, stream>>>(bsum, boff, nb_n);
    scan3_k<<<nb_n, 256, 0, stream>>>(deg, indptr, boff, cursor, srcs, N);
    fill_edge_k<<<nb_e, 256, 0, stream>>>(esrc, edst, cursor, srcs, E);
    prep_w_k<<<256, 256, 0, stream>>>(W1, WTh1);
    prep_w_k<<<256, 256, 0, stream>>>(W2, WTh2);

    // layer 1
    gemm_mfma_k<1><<<nb_g, 512, 0, stream>>>(x, WTh1, as1, ad1, hbuf, aS, aD, N);
    agg_k<0><<<nb_w, 256, 0, stream>>>(hbuf, aS, aD, indptr, srcs, b1, xnext,
                                       nullptr, nullptr, nullptr, nullptr, nullptr, nullptr, N);
    // layer 2 (+ fused layer-3 matvec)
    gemm_mfma_k<0><<<nb_g, 512, 0, stream>>>(xnext, WTh2, as2, ad2, hbuf, aS, aD, N);
    agg_k<1><<<nb_w, 256, 0, stream>>>(hbuf, aS, aD, indptr, srcs, b2, nullptr,
                                       W3, at_s3, at_d3, h3, s3, d3, N);
    // layer 3 aggregation
    agg3_k<<<nb_a3, 256, 0, stream>>>(h3, s3, d3, indptr, srcs, b3, (float*)d_out, N);
}